// Round 6
// baseline (91.363 us; speedup 1.0000x reference)
//
#include <hip/hip_runtime.h>

constexpr int B  = 2;
constexpr int L  = 256;
constexpr int Dd = 512;
constexpr int Hh = 256;
constexpr int Oo = 16;
constexpr int BL = B * L;
constexpr int NBO = B * Oo;          // 32
constexpr int SLAB = NBO * L;        // 8192 floats per partial slot
constexpr int NBLK = 512;            // total workgroups (2 per CU x 256 CUs)

__device__ __forceinline__ float dot4(const float4 a, const float4 b) {
    return a.x * b.x + a.y * b.y + a.z * b.z + a.w * b.w;
}
__device__ __forceinline__ float leaky(const float v) {
    return (v >= 0.f) ? v : 0.1f * v;
}

// Device-scope grid barrier (persistent-kernel pattern; all NBLK blocks are
// co-resident by construction: __launch_bounds__(256,2) on a 512-block grid).
// bar[0]=arrive count, bar[1]=generation; both zeroed via hipMemsetAsync
// before launch. Release/acquire + __threadfence for cross-XCD visibility.
__device__ __forceinline__ void grid_barrier(unsigned* bar) {
    __syncthreads();
    if (threadIdx.x == 0) {
        __threadfence();   // make this block's global stores device-visible
        const unsigned g = __hip_atomic_load(bar + 1, __ATOMIC_ACQUIRE,
                                             __HIP_MEMORY_SCOPE_AGENT);
        const unsigned prev = __hip_atomic_fetch_add(bar, 1u, __ATOMIC_ACQ_REL,
                                                     __HIP_MEMORY_SCOPE_AGENT);
        if (prev == (unsigned)NBLK - 1) {
            __hip_atomic_store(bar, 0u, __ATOMIC_RELAXED,
                               __HIP_MEMORY_SCOPE_AGENT);
            __hip_atomic_fetch_add(bar + 1, 1u, __ATOMIC_RELEASE,
                                   __HIP_MEMORY_SCOPE_AGENT);
        } else {
            while (__hip_atomic_load(bar + 1, __ATOMIC_ACQUIRE,
                                     __HIP_MEMORY_SCOPE_AGENT) == g) {
                __builtin_amdgcn_s_sleep(2);
            }
        }
        __threadfence();   // acquire: don't serve stale lines after the wait
    }
    __syncthreads();
}

// ---------------------------------------------------------------------------
// Single kernel, grid (64,4,2) = 512 blocks x 256 thr, 2 blocks/CU.
// Phase 1 (identical to R4 K1): MLP GEMM (x-tile in LDS, shfl_xor k-reduce),
// h kept in LDS, partial projections onto Wf -> PA/PB/PD slots.
// grid_barrier
// Phase 2 (identical to R4 K2): reduce partial slots, Hillis-Steele scan of
// D -> C, write 16x256 tile:
//   out[bo,i,j] = A[j] + Bv[i] + bf[o] + (C[j]-C[i-1])/(j-i+1+1e-9)
// i = j+1 numerator exactly 0 (identical LDS values) -> no 1e9 blowup.
// ---------------------------------------------------------------------------
__global__ __launch_bounds__(256, 2) void fused_kernel(
    const float* __restrict__ x,
    const float* __restrict__ W1, const float* __restrict__ b1,
    const float* __restrict__ W2, const float* __restrict__ b2,
    const float* __restrict__ Wf, const float* __restrict__ bf,
    float* __restrict__ PA, float* __restrict__ PB, float* __restrict__ PD,
    unsigned* __restrict__ bar,
    float* __restrict__ out)
{
    __shared__ float xs[8 * Dd];       // 16 KB
    __shared__ float hbuf[8][64];      // 2 KB
    __shared__ float Asm[L], Bsm[L], ca[L], cb[L];  // 4 KB (phase 2)

    const int t = threadIdx.x;

    // ===================== Phase 1: MLP + partial projection ================
    {
        const int rs = blockIdx.x;   // rowset: 8 bl-rows
        const int hc = blockIdx.y;   // h-chunk: 64 h
        const int m  = blockIdx.z;
        const float* __restrict__ W  = m ? W2 : W1;
        const float* __restrict__ bb = m ? b2 : b1;

        {
            const float4* xg = reinterpret_cast<const float4*>(x + (size_t)rs * 8 * Dd);
            float4* s4 = reinterpret_cast<float4*>(xs);
            #pragma unroll
            for (int i = 0; i < 4; ++i) s4[t + 256 * i] = xg[t + 256 * i];
        }
        __syncthreads();

        const int wave = t >> 6, lane = t & 63, g = lane >> 4, kl = lane & 15;
        const int h0 = hc * 64 + wave * 16 + g * 4;

        const float4* w0 = reinterpret_cast<const float4*>(W + (size_t)(h0 + 0) * Dd);
        const float4* w1 = reinterpret_cast<const float4*>(W + (size_t)(h0 + 1) * Dd);
        const float4* w2 = reinterpret_cast<const float4*>(W + (size_t)(h0 + 2) * Dd);
        const float4* w3 = reinterpret_cast<const float4*>(W + (size_t)(h0 + 3) * Dd);
        const float4* xs4 = reinterpret_cast<const float4*>(xs);

        float acc[8][4];
        #pragma unroll
        for (int r = 0; r < 8; ++r)
            #pragma unroll
            for (int j = 0; j < 4; ++j) acc[r][j] = 0.f;

        #pragma unroll
        for (int s = 0; s < 8; ++s) {
            const int ko = s * 16 + kl;
            const float4 a = w0[ko], b_ = w1[ko], c = w2[ko], d = w3[ko];
            #pragma unroll
            for (int r = 0; r < 8; ++r) {
                const float4 xv = xs4[r * 128 + ko];
                acc[r][0] += dot4(xv, a);
                acc[r][1] += dot4(xv, b_);
                acc[r][2] += dot4(xv, c);
                acc[r][3] += dot4(xv, d);
            }
        }

        #pragma unroll
        for (int r = 0; r < 8; ++r)
            #pragma unroll
            for (int j = 0; j < 4; ++j) {
                float v = acc[r][j];
                v += __shfl_xor(v, 1); v += __shfl_xor(v, 2);
                v += __shfl_xor(v, 4); v += __shfl_xor(v, 8);
                acc[r][j] = v;
            }

        if (kl == 0) {
            const float4 bv = *reinterpret_cast<const float4*>(bb + h0);
            const int hl = wave * 16 + g * 4;
            #pragma unroll
            for (int r = 0; r < 8; ++r) {
                float4 o;
                o.x = leaky(acc[r][0] + bv.x);
                o.y = leaky(acc[r][1] + bv.y);
                o.z = leaky(acc[r][2] + bv.z);
                o.w = leaky(acc[r][3] + bv.w);
                *reinterpret_cast<float4*>(&hbuf[r][hl]) = o;
            }
        }
        __syncthreads();

        if (t < 128) {
            const int r = t >> 4, o = t & 15;
            const float4* wf1 = reinterpret_cast<const float4*>(Wf + (size_t)o * (3 * Hh) + hc * 64);
            const float4* wf2 = reinterpret_cast<const float4*>(Wf + (size_t)o * (3 * Hh) + Hh + hc * 64);
            const float4* wf3 = reinterpret_cast<const float4*>(Wf + (size_t)o * (3 * Hh) + 2 * Hh + hc * 64);
            const float4* hv  = reinterpret_cast<const float4*>(&hbuf[r][0]);

            float s1 = 0.f, s2 = 0.f, s3 = 0.f;
            #pragma unroll
            for (int k = 0; k < 16; ++k) {
                const float4 h4 = hv[k];
                s1 += dot4(wf1[k], h4);
                s2 += dot4(wf2[k], h4);
                if (m == 0) s3 += dot4(wf3[k], h4);
            }

            const int bl = rs * 8 + r;
            const int b = bl >> 8, l = bl & 255;
            const size_t idx = ((size_t)(b * Oo + o)) * L + l;
            if (m == 0) {
                PA[(size_t)hc * SLAB + idx] = s1;
                PB[(size_t)hc * SLAB + idx] = 0.5f * s2;
                PD[(size_t)hc * SLAB + idx] = s3;
            } else {
                PA[(size_t)(4 + hc) * SLAB + idx] = 0.5f * s2;
                PB[(size_t)(4 + hc) * SLAB + idx] = -s1;
            }
        }
    }

    grid_barrier(bar);

    // ===================== Phase 2: reduce + scan + epilogue ================
    {
        const int flat = blockIdx.x + 64 * (blockIdx.y + 4 * blockIdx.z); // 0..511
        const int bo = flat >> 4;    // 0..31
        const int ig = flat & 15;    // i-chunk of 16

        {
            float a = 0.f, bsum = 0.f, d = 0.f;
            #pragma unroll
            for (int s = 0; s < 8; ++s) {
                a    += PA[(size_t)s * SLAB + (size_t)bo * L + t];
                bsum += PB[(size_t)s * SLAB + (size_t)bo * L + t];
            }
            #pragma unroll
            for (int s = 0; s < 4; ++s)
                d += PD[(size_t)s * SLAB + (size_t)bo * L + t];
            Asm[t] = a; Bsm[t] = bsum; ca[t] = d;
        }
        __syncthreads();

        float* src = ca;
        float* dst = cb;
        #pragma unroll
        for (int off = 1; off < L; off <<= 1) {
            const float s = src[t] + ((t >= off) ? src[t - off] : 0.f);
            dst[t] = s;
            __syncthreads();
            float* tmp = src; src = dst; dst = tmp;
        }
        // src[l] = inclusive prefix C[l]

        const float bfv = bf[bo & (Oo - 1)];
        const int j0 = (t & 63) * 4;
        const int is = t >> 6;

        const float4 Av = *reinterpret_cast<const float4*>(Asm + j0);
        const float4 Cv = *reinterpret_cast<const float4*>(src + j0);

        #pragma unroll
        for (int ii = 0; ii < 4; ++ii) {
            const int i = ig * 16 + is * 4 + ii;
            const float cp   = (i > 0) ? src[i - 1] : 0.f;
            const float base = Bsm[i] + bfv;
            float4 r;
            r.x = Av.x + base + (Cv.x - cp) / ((float)(j0 + 0 - i + 1) + 1e-9f);
            r.y = Av.y + base + (Cv.y - cp) / ((float)(j0 + 1 - i + 1) + 1e-9f);
            r.z = Av.z + base + (Cv.z - cp) / ((float)(j0 + 2 - i + 1) + 1e-9f);
            r.w = Av.w + base + (Cv.w - cp) / ((float)(j0 + 3 - i + 1) + 1e-9f);
            *reinterpret_cast<float4*>(out + ((size_t)bo * L + i) * L + j0) = r;
        }
    }
}

// ---------------------------------------------------------------------------
extern "C" void kernel_launch(void* const* d_in, const int* in_sizes, int n_in,
                              void* d_out, int out_size, void* d_ws, size_t ws_size,
                              hipStream_t stream)
{
    const float* x  = (const float*)d_in[0];
    const float* W1 = (const float*)d_in[1];
    const float* b1 = (const float*)d_in[2];
    const float* W2 = (const float*)d_in[3];
    const float* b2 = (const float*)d_in[4];
    const float* Wf = (const float*)d_in[5];
    const float* bf = (const float*)d_in[6];
    float* out = (float*)d_out;

    float* ws = (float*)d_ws;
    float* PA = ws;                       // 8 * SLAB
    float* PB = PA + 8 * (size_t)SLAB;    // 8 * SLAB
    float* PD = PB + 8 * (size_t)SLAB;    // 4 * SLAB
    unsigned* bar = (unsigned*)(PD + 4 * (size_t)SLAB);  // 2 uints

    hipMemsetAsync(bar, 0, 2 * sizeof(unsigned), stream);
    hipLaunchKernelGGL(fused_kernel, dim3(64, 4, 2), dim3(256), 0, stream,
                       x, W1, b1, W2, b2, Wf, bf, PA, PB, PD, bar, out);
}

// Round 7
// 35.971 us; speedup vs baseline: 2.5399x; 2.5399x over previous
//
#include <hip/hip_runtime.h>

constexpr int B  = 2;
constexpr int L  = 256;
constexpr int Dd = 512;
constexpr int Hh = 256;
constexpr int Oo = 16;
constexpr int BL = B * L;
constexpr int NBO = B * Oo;          // 32
constexpr int SLAB = NBO * L;        // 8192 floats per partial slot

__device__ __forceinline__ float dot4(const float4 a, const float4 b) {
    return a.x * b.x + a.y * b.y + a.z * b.z + a.w * b.w;
}
__device__ __forceinline__ float leaky(const float v) {
    return (v >= 0.f) ? v : 0.1f * v;
}

// ---------------------------------------------------------------------------
// K1: fused MLP + partial projection, re-tiled for occupancy.
// grid = (128 rowsets of 4, 4 h-chunks of 64, 2 matrices) = 1024 blocks,
// 256 thr, __launch_bounds__(256,4) -> 4 blocks/CU = 4 waves/SIMD (2x the
// latency hiding of the R4 shape; W-L2 stream ~3.8us aggregate overlaps).
// Wave = 4 h-groups x 16 k-lanes; lane owns 4 W rows; x-tile (4 rows, 8 KB)
// in LDS; shfl_xor(1/2/4/8) k-reduction. h kept in LDS only.
// Phase B: thread (r,o) in t<64 projects the 64-h slice onto Wf ->
//   m=0: PA[hc]=Wf1.h, PB[hc]=0.5*Wf2.h, PD[hc]=Wf3.h
//   m=1: PA[4+hc]=0.5*Wf2.h, PB[4+hc]=-Wf1.h
// ---------------------------------------------------------------------------
__global__ __launch_bounds__(256, 4) void mlp_proj_kernel(
    const float* __restrict__ x,
    const float* __restrict__ W1, const float* __restrict__ b1,
    const float* __restrict__ W2, const float* __restrict__ b2,
    const float* __restrict__ Wf,
    float* __restrict__ PA, float* __restrict__ PB, float* __restrict__ PD)
{
    const int rs = blockIdx.x;   // rowset: 4 bl-rows
    const int hc = blockIdx.y;   // h-chunk: 64 h
    const int m  = blockIdx.z;
    const float* __restrict__ W  = m ? W2 : W1;
    const float* __restrict__ bb = m ? b2 : b1;

    __shared__ float xs[4 * Dd];       // 8 KB
    __shared__ float hbuf[4][64];      // 1 KB
    const int t = threadIdx.x;
    {
        const float4* xg = reinterpret_cast<const float4*>(x + (size_t)rs * 4 * Dd);
        float4* s4 = reinterpret_cast<float4*>(xs);
        s4[t]       = xg[t];
        s4[t + 256] = xg[t + 256];
    }
    __syncthreads();

    const int wave = t >> 6, lane = t & 63, g = lane >> 4, kl = lane & 15;
    const int h0 = hc * 64 + wave * 16 + g * 4;

    const float4* w0 = reinterpret_cast<const float4*>(W + (size_t)(h0 + 0) * Dd);
    const float4* w1 = reinterpret_cast<const float4*>(W + (size_t)(h0 + 1) * Dd);
    const float4* w2 = reinterpret_cast<const float4*>(W + (size_t)(h0 + 2) * Dd);
    const float4* w3 = reinterpret_cast<const float4*>(W + (size_t)(h0 + 3) * Dd);
    const float4* xs4 = reinterpret_cast<const float4*>(xs);

    float acc[4][4];
    #pragma unroll
    for (int r = 0; r < 4; ++r)
        #pragma unroll
        for (int j = 0; j < 4; ++j) acc[r][j] = 0.f;

    #pragma unroll
    for (int s = 0; s < 8; ++s) {
        const int ko = s * 16 + kl;
        const float4 a = w0[ko], b_ = w1[ko], c = w2[ko], d = w3[ko];
        #pragma unroll
        for (int r = 0; r < 4; ++r) {
            const float4 xv = xs4[r * 128 + ko];
            acc[r][0] += dot4(xv, a);
            acc[r][1] += dot4(xv, b_);
            acc[r][2] += dot4(xv, c);
            acc[r][3] += dot4(xv, d);
        }
    }

    #pragma unroll
    for (int r = 0; r < 4; ++r)
        #pragma unroll
        for (int j = 0; j < 4; ++j) {
            float v = acc[r][j];
            v += __shfl_xor(v, 1); v += __shfl_xor(v, 2);
            v += __shfl_xor(v, 4); v += __shfl_xor(v, 8);
            acc[r][j] = v;
        }

    if (kl == 0) {
        const float4 bv = *reinterpret_cast<const float4*>(bb + h0);
        const int hl = wave * 16 + g * 4;
        #pragma unroll
        for (int r = 0; r < 4; ++r) {
            float4 o;
            o.x = leaky(acc[r][0] + bv.x);
            o.y = leaky(acc[r][1] + bv.y);
            o.z = leaky(acc[r][2] + bv.z);
            o.w = leaky(acc[r][3] + bv.w);
            *reinterpret_cast<float4*>(&hbuf[r][hl]) = o;
        }
    }
    __syncthreads();

    // Phase B: partial projections over the 64-h slice (one wave).
    if (t < 64) {
        const int r = t >> 4, o = t & 15;
        const float4* wf1 = reinterpret_cast<const float4*>(Wf + (size_t)o * (3 * Hh) + hc * 64);
        const float4* wf2 = reinterpret_cast<const float4*>(Wf + (size_t)o * (3 * Hh) + Hh + hc * 64);
        const float4* wf3 = reinterpret_cast<const float4*>(Wf + (size_t)o * (3 * Hh) + 2 * Hh + hc * 64);
        const float4* hv  = reinterpret_cast<const float4*>(&hbuf[r][0]);

        float s1 = 0.f, s2 = 0.f, s3 = 0.f;
        #pragma unroll
        for (int k = 0; k < 16; ++k) {
            const float4 h4 = hv[k];
            s1 += dot4(wf1[k], h4);
            s2 += dot4(wf2[k], h4);
            if (m == 0) s3 += dot4(wf3[k], h4);
        }

        const int bl = rs * 4 + r;
        const int b = bl >> 8, l = bl & 255;
        const size_t idx = ((size_t)(b * Oo + o)) * L + l;
        if (m == 0) {
            PA[(size_t)hc * SLAB + idx] = s1;
            PB[(size_t)hc * SLAB + idx] = 0.5f * s2;
            PD[(size_t)hc * SLAB + idx] = s3;
        } else {
            PA[(size_t)(4 + hc) * SLAB + idx] = 0.5f * s2;
            PB[(size_t)(4 + hc) * SLAB + idx] = -s1;
        }
    }
}

// ---------------------------------------------------------------------------
// K2: partial-reduce + cumsum + epilogue. grid = 32 bo x 16 i-chunks = 512.
// Reduce 8 PA/PB slots and 4 PD slots (coalesced over l = t), Hillis-Steele
// scan of D in LDS -> C, write the 16 x 256 tile:
//   out[bo,i,j] = A[j] + Bv[i] + bf[o] + (C[j]-C[i-1])/(j-i+1+1e-9)
// i = j+1 numerator exactly 0 (identical LDS values) -> no 1e9 blowup.
// ---------------------------------------------------------------------------
__global__ __launch_bounds__(256) void out_kernel(
    const float* __restrict__ PA, const float* __restrict__ PB,
    const float* __restrict__ PD, const float* __restrict__ bf,
    float* __restrict__ out)
{
    const int bo = blockIdx.x >> 4;    // 0..31
    const int ig = blockIdx.x & 15;    // i-chunk of 16
    const int t  = threadIdx.x;

    __shared__ float Asm[L], Bsm[L], ca[L], cb[L];
    {
        float a = 0.f, bsum = 0.f, d = 0.f;
        #pragma unroll
        for (int s = 0; s < 8; ++s) {
            a    += PA[(size_t)s * SLAB + (size_t)bo * L + t];
            bsum += PB[(size_t)s * SLAB + (size_t)bo * L + t];
        }
        #pragma unroll
        for (int s = 0; s < 4; ++s)
            d += PD[(size_t)s * SLAB + (size_t)bo * L + t];
        Asm[t] = a; Bsm[t] = bsum; ca[t] = d;
    }
    __syncthreads();

    float* src = ca;
    float* dst = cb;
    #pragma unroll
    for (int off = 1; off < L; off <<= 1) {
        const float s = src[t] + ((t >= off) ? src[t - off] : 0.f);
        dst[t] = s;
        __syncthreads();
        float* tmp = src; src = dst; dst = tmp;
    }
    // src[l] = inclusive prefix C[l]

    const float bfv = bf[bo & (Oo - 1)];
    const int j0 = (t & 63) * 4;
    const int is = t >> 6;

    const float4 Av = *reinterpret_cast<const float4*>(Asm + j0);
    const float4 Cv = *reinterpret_cast<const float4*>(src + j0);

    #pragma unroll
    for (int ii = 0; ii < 4; ++ii) {
        const int i = ig * 16 + is * 4 + ii;
        const float cp   = (i > 0) ? src[i - 1] : 0.f;
        const float base = Bsm[i] + bfv;
        float4 r;
        r.x = Av.x + base + (Cv.x - cp) / ((float)(j0 + 0 - i + 1) + 1e-9f);
        r.y = Av.y + base + (Cv.y - cp) / ((float)(j0 + 1 - i + 1) + 1e-9f);
        r.z = Av.z + base + (Cv.z - cp) / ((float)(j0 + 2 - i + 1) + 1e-9f);
        r.w = Av.w + base + (Cv.w - cp) / ((float)(j0 + 3 - i + 1) + 1e-9f);
        *reinterpret_cast<float4*>(out + ((size_t)bo * L + i) * L + j0) = r;
    }
}

// ---------------------------------------------------------------------------
extern "C" void kernel_launch(void* const* d_in, const int* in_sizes, int n_in,
                              void* d_out, int out_size, void* d_ws, size_t ws_size,
                              hipStream_t stream)
{
    const float* x  = (const float*)d_in[0];
    const float* W1 = (const float*)d_in[1];
    const float* b1 = (const float*)d_in[2];
    const float* W2 = (const float*)d_in[3];
    const float* b2 = (const float*)d_in[4];
    const float* Wf = (const float*)d_in[5];
    const float* bf = (const float*)d_in[6];
    float* out = (float*)d_out;

    float* ws = (float*)d_ws;
    float* PA = ws;                       // 8 * SLAB
    float* PB = PA + 8 * (size_t)SLAB;    // 8 * SLAB
    float* PD = PB + 8 * (size_t)SLAB;    // 4 * SLAB

    hipLaunchKernelGGL(mlp_proj_kernel, dim3(BL / 4, 4, 2), dim3(256), 0, stream,
                       x, W1, b1, W2, b2, Wf, PA, PB, PD);
    hipLaunchKernelGGL(out_kernel, dim3(NBO * 16), dim3(256), 0, stream,
                       PA, PB, PD, bf, out);
}

// Round 8
// 26.054 us; speedup vs baseline: 3.5067x; 1.3806x over previous
//
#include <hip/hip_runtime.h>

constexpr int B  = 2;
constexpr int L  = 256;
constexpr int Dd = 512;
constexpr int Hh = 256;
constexpr int Oo = 16;
constexpr int BL = B * L;
constexpr int NBO = B * Oo;          // 32
constexpr int SLAB = NBO * L;        // 8192 floats per partial slot
constexpr int RPB  = 16;             // rows per block (K1)

__device__ __forceinline__ float dot4(const float4 a, const float4 b) {
    return a.x * b.x + a.y * b.y + a.z * b.z + a.w * b.w;
}
__device__ __forceinline__ float leaky(const float v) {
    return (v >= 0.f) ? v : 0.1f * v;
}

// ---------------------------------------------------------------------------
// K1: fused MLP + partial projection, W-traffic-minimized tile.
// grid = (32 rowsets of 16, 4 h-chunks of 64, 2 matrices) = 256 blocks
// (exactly 1/CU), 256 thr. W-from-L2 = 256 x 128 KB = 32 MB (R4: 64, R7: 128
// — the measured regression variable). Lane owns 4 W rows; per k-step the 4
// W float4s are reused across 16 x-rows = 64 dot4 per 4 W loads (4x R4's
// compute:load ratio; the 64 independent FMA chains are the latency hiding).
// x-tile (16 rows, 32 KB) in LDS; shfl_xor(1/2/4/8) k-reduction; h in LDS.
// Phase B: all 256 thr (r,o) project the 64-h slice onto Wf:
//   m=0: PA[hc]=Wf1.h, PB[hc]=0.5*Wf2.h, PD[hc]=Wf3.h
//   m=1: PA[4+hc]=0.5*Wf2.h, PB[4+hc]=-Wf1.h
// ---------------------------------------------------------------------------
__global__ __launch_bounds__(256) void mlp_proj_kernel(
    const float* __restrict__ x,
    const float* __restrict__ W1, const float* __restrict__ b1,
    const float* __restrict__ W2, const float* __restrict__ b2,
    const float* __restrict__ Wf,
    float* __restrict__ PA, float* __restrict__ PB, float* __restrict__ PD)
{
    const int rs = blockIdx.x;   // rowset: 16 bl-rows
    const int hc = blockIdx.y;   // h-chunk: 64 h
    const int m  = blockIdx.z;
    const float* __restrict__ W  = m ? W2 : W1;
    const float* __restrict__ bb = m ? b2 : b1;

    __shared__ float xs[RPB * Dd];     // 32 KB
    __shared__ float hbuf[RPB][64];    // 4 KB
    const int t = threadIdx.x;
    {
        const float4* xg = reinterpret_cast<const float4*>(x + (size_t)rs * RPB * Dd);
        float4* s4 = reinterpret_cast<float4*>(xs);
        #pragma unroll
        for (int i = 0; i < RPB * Dd / 4 / 256; ++i)
            s4[t + 256 * i] = xg[t + 256 * i];
    }
    __syncthreads();

    const int wave = t >> 6, lane = t & 63, g = lane >> 4, kl = lane & 15;
    const int h0 = hc * 64 + wave * 16 + g * 4;

    const float4* w0 = reinterpret_cast<const float4*>(W + (size_t)(h0 + 0) * Dd);
    const float4* w1 = reinterpret_cast<const float4*>(W + (size_t)(h0 + 1) * Dd);
    const float4* w2 = reinterpret_cast<const float4*>(W + (size_t)(h0 + 2) * Dd);
    const float4* w3 = reinterpret_cast<const float4*>(W + (size_t)(h0 + 3) * Dd);
    const float4* xs4 = reinterpret_cast<const float4*>(xs);

    float acc[RPB][4];
    #pragma unroll
    for (int r = 0; r < RPB; ++r)
        #pragma unroll
        for (int j = 0; j < 4; ++j) acc[r][j] = 0.f;

    for (int s = 0; s < 8; ++s) {
        const int ko = s * 16 + kl;
        const float4 a = w0[ko], b_ = w1[ko], c = w2[ko], d = w3[ko];
        #pragma unroll
        for (int r = 0; r < RPB; ++r) {
            const float4 xv = xs4[r * 128 + ko];
            acc[r][0] += dot4(xv, a);
            acc[r][1] += dot4(xv, b_);
            acc[r][2] += dot4(xv, c);
            acc[r][3] += dot4(xv, d);
        }
    }

    #pragma unroll
    for (int r = 0; r < RPB; ++r)
        #pragma unroll
        for (int j = 0; j < 4; ++j) {
            float v = acc[r][j];
            v += __shfl_xor(v, 1); v += __shfl_xor(v, 2);
            v += __shfl_xor(v, 4); v += __shfl_xor(v, 8);
            acc[r][j] = v;
        }

    if (kl == 0) {
        const float4 bv = *reinterpret_cast<const float4*>(bb + h0);
        const int hl = wave * 16 + g * 4;
        #pragma unroll
        for (int r = 0; r < RPB; ++r) {
            float4 o;
            o.x = leaky(acc[r][0] + bv.x);
            o.y = leaky(acc[r][1] + bv.y);
            o.z = leaky(acc[r][2] + bv.z);
            o.w = leaky(acc[r][3] + bv.w);
            *reinterpret_cast<float4*>(&hbuf[r][hl]) = o;
        }
    }
    __syncthreads();

    // Phase B: partial projections over the 64-h slice (all 256 threads).
    {
        const int r = t >> 4, o = t & 15;
        const float4* wf1 = reinterpret_cast<const float4*>(Wf + (size_t)o * (3 * Hh) + hc * 64);
        const float4* wf2 = reinterpret_cast<const float4*>(Wf + (size_t)o * (3 * Hh) + Hh + hc * 64);
        const float4* wf3 = reinterpret_cast<const float4*>(Wf + (size_t)o * (3 * Hh) + 2 * Hh + hc * 64);
        const float4* hv  = reinterpret_cast<const float4*>(&hbuf[r][0]);

        float s1 = 0.f, s2 = 0.f, s3 = 0.f;
        #pragma unroll
        for (int k = 0; k < 16; ++k) {
            const float4 h4 = hv[k];
            s1 += dot4(wf1[k], h4);
            s2 += dot4(wf2[k], h4);
            if (m == 0) s3 += dot4(wf3[k], h4);
        }

        const int bl = rs * RPB + r;
        const int b = bl >> 8, l = bl & 255;
        const size_t idx = ((size_t)(b * Oo + o)) * L + l;
        if (m == 0) {
            PA[(size_t)hc * SLAB + idx] = s1;
            PB[(size_t)hc * SLAB + idx] = 0.5f * s2;
            PD[(size_t)hc * SLAB + idx] = s3;
        } else {
            PA[(size_t)(4 + hc) * SLAB + idx] = 0.5f * s2;
            PB[(size_t)(4 + hc) * SLAB + idx] = -s1;
        }
    }
}

// ---------------------------------------------------------------------------
// K2: partial-reduce + cumsum + epilogue (byte-identical to R4/R7).
// grid = 32 bo x 16 i-chunks = 512 blocks, 256 thr.
//   out[bo,i,j] = A[j] + Bv[i] + bf[o] + (C[j]-C[i-1])/(j-i+1+1e-9)
// i = j+1 numerator exactly 0 (identical LDS values) -> no 1e9 blowup.
// ---------------------------------------------------------------------------
__global__ __launch_bounds__(256) void out_kernel(
    const float* __restrict__ PA, const float* __restrict__ PB,
    const float* __restrict__ PD, const float* __restrict__ bf,
    float* __restrict__ out)
{
    const int bo = blockIdx.x >> 4;    // 0..31
    const int ig = blockIdx.x & 15;    // i-chunk of 16
    const int t  = threadIdx.x;

    __shared__ float Asm[L], Bsm[L], ca[L], cb[L];
    {
        float a = 0.f, bsum = 0.f, d = 0.f;
        #pragma unroll
        for (int s = 0; s < 8; ++s) {
            a    += PA[(size_t)s * SLAB + (size_t)bo * L + t];
            bsum += PB[(size_t)s * SLAB + (size_t)bo * L + t];
        }
        #pragma unroll
        for (int s = 0; s < 4; ++s)
            d += PD[(size_t)s * SLAB + (size_t)bo * L + t];
        Asm[t] = a; Bsm[t] = bsum; ca[t] = d;
    }
    __syncthreads();

    float* src = ca;
    float* dst = cb;
    #pragma unroll
    for (int off = 1; off < L; off <<= 1) {
        const float s = src[t] + ((t >= off) ? src[t - off] : 0.f);
        dst[t] = s;
        __syncthreads();
        float* tmp = src; src = dst; dst = tmp;
    }
    // src[l] = inclusive prefix C[l]

    const float bfv = bf[bo & (Oo - 1)];
    const int j0 = (t & 63) * 4;
    const int is = t >> 6;

    const float4 Av = *reinterpret_cast<const float4*>(Asm + j0);
    const float4 Cv = *reinterpret_cast<const float4*>(src + j0);

    #pragma unroll
    for (int ii = 0; ii < 4; ++ii) {
        const int i = ig * 16 + is * 4 + ii;
        const float cp   = (i > 0) ? src[i - 1] : 0.f;
        const float base = Bsm[i] + bfv;
        float4 r;
        r.x = Av.x + base + (Cv.x - cp) / ((float)(j0 + 0 - i + 1) + 1e-9f);
        r.y = Av.y + base + (Cv.y - cp) / ((float)(j0 + 1 - i + 1) + 1e-9f);
        r.z = Av.z + base + (Cv.z - cp) / ((float)(j0 + 2 - i + 1) + 1e-9f);
        r.w = Av.w + base + (Cv.w - cp) / ((float)(j0 + 3 - i + 1) + 1e-9f);
        *reinterpret_cast<float4*>(out + ((size_t)bo * L + i) * L + j0) = r;
    }
}

// ---------------------------------------------------------------------------
extern "C" void kernel_launch(void* const* d_in, const int* in_sizes, int n_in,
                              void* d_out, int out_size, void* d_ws, size_t ws_size,
                              hipStream_t stream)
{
    const float* x  = (const float*)d_in[0];
    const float* W1 = (const float*)d_in[1];
    const float* b1 = (const float*)d_in[2];
    const float* W2 = (const float*)d_in[3];
    const float* b2 = (const float*)d_in[4];
    const float* Wf = (const float*)d_in[5];
    const float* bf = (const float*)d_in[6];
    float* out = (float*)d_out;

    float* ws = (float*)d_ws;
    float* PA = ws;                       // 8 * SLAB
    float* PB = PA + 8 * (size_t)SLAB;    // 8 * SLAB
    float* PD = PB + 8 * (size_t)SLAB;    // 4 * SLAB

    hipLaunchKernelGGL(mlp_proj_kernel, dim3(BL / RPB, 4, 2), dim3(256), 0, stream,
                       x, W1, b1, W2, b2, Wf, PA, PB, PD);
    hipLaunchKernelGGL(out_kernel, dim3(NBO * 16), dim3(256), 0, stream,
                       PA, PB, PD, bf, out);
}

// Round 9
// 21.007 us; speedup vs baseline: 4.3492x; 1.2403x over previous
//
#include <hip/hip_runtime.h>

constexpr int B  = 2;
constexpr int L  = 256;
constexpr int Dd = 512;
constexpr int Hh = 256;
constexpr int Oo = 16;
constexpr int BL = B * L;
constexpr int NBO = B * Oo;          // 32
constexpr int SLAB = NBO * L;        // 8192 floats per partial slot

__device__ __forceinline__ float leaky(const float v) {
    return (v >= 0.f) ? v : 0.1f * v;
}
__device__ __forceinline__ void fma4(float& acc, const float4 a, const float4 b) {
    acc = fmaf(a.x, b.x, acc);
    acc = fmaf(a.y, b.y, acc);
    acc = fmaf(a.z, b.z, acc);
    acc = fmaf(a.w, b.w, acc);
}
__device__ __forceinline__ float dot4(const float4 a, const float4 b) {
    float s = 0.f; fma4(s, a, b); return s;
}

// Sum across each row-of-16 lanes using DPP row-rotates: runs on the VALU
// pipe (v_add_f32 + dpp), NOT the DS pipe like __shfl_xor/ds_swizzle.
// row_ror:N = dpp_ctrl 0x120+N; rotations within a 16-lane row form a
// complete reduction (every lane ends with the full 16-sum).
__device__ __forceinline__ float red16(float v) {
    v += __int_as_float(__builtin_amdgcn_update_dpp(
            0, __float_as_int(v), 0x128, 0xF, 0xF, true)); // row_ror:8
    v += __int_as_float(__builtin_amdgcn_update_dpp(
            0, __float_as_int(v), 0x124, 0xF, 0xF, true)); // row_ror:4
    v += __int_as_float(__builtin_amdgcn_update_dpp(
            0, __float_as_int(v), 0x122, 0xF, 0xF, true)); // row_ror:2
    v += __int_as_float(__builtin_amdgcn_update_dpp(
            0, __float_as_int(v), 0x121, 0xF, 0xF, true)); // row_ror:1
    return v;
}

// ---------------------------------------------------------------------------
// K1: fused MLP + partial projection (R4 structure, DS-pipe-relieved).
// grid = (64 rowsets of 8, 4 h-chunks of 64, 2 matrices) = 512 blocks,
// 256 thr, 2 blocks/CU. Wave = 4 h-groups x 16 k-lanes; lane owns 4 W rows.
// x-tile (8 rows, 16 KB) in LDS; k-reduction via DPP (VALU pipe).
// Phase B: thread (r,o) in t<128 projects the 64-h slice onto Wf:
//   m=0: PA[hc]=Wf1.h, PB[hc]=0.5*Wf2.h, PD[hc]=Wf3.h
//   m=1: PA[4+hc]=0.5*Wf2.h, PB[4+hc]=-Wf1.h
// ---------------------------------------------------------------------------
__global__ __launch_bounds__(256, 2) void mlp_proj_kernel(
    const float* __restrict__ x,
    const float* __restrict__ W1, const float* __restrict__ b1,
    const float* __restrict__ W2, const float* __restrict__ b2,
    const float* __restrict__ Wf,
    float* __restrict__ PA, float* __restrict__ PB, float* __restrict__ PD)
{
    const int rs = blockIdx.x;   // rowset: 8 bl-rows
    const int hc = blockIdx.y;   // h-chunk: 64 h
    const int m  = blockIdx.z;
    const float* __restrict__ W  = m ? W2 : W1;
    const float* __restrict__ bb = m ? b2 : b1;

    __shared__ float xs[8 * Dd];       // 16 KB
    __shared__ float hbuf[8][64];      // 2 KB
    const int t = threadIdx.x;
    {
        const float4* xg = reinterpret_cast<const float4*>(x + (size_t)rs * 8 * Dd);
        float4* s4 = reinterpret_cast<float4*>(xs);
        #pragma unroll
        for (int i = 0; i < 4; ++i) s4[t + 256 * i] = xg[t + 256 * i];
    }
    __syncthreads();

    const int wave = t >> 6, lane = t & 63, g = lane >> 4, kl = lane & 15;
    const int h0 = hc * 64 + wave * 16 + g * 4;

    const float4* w0 = reinterpret_cast<const float4*>(W + (size_t)(h0 + 0) * Dd);
    const float4* w1 = reinterpret_cast<const float4*>(W + (size_t)(h0 + 1) * Dd);
    const float4* w2 = reinterpret_cast<const float4*>(W + (size_t)(h0 + 2) * Dd);
    const float4* w3 = reinterpret_cast<const float4*>(W + (size_t)(h0 + 3) * Dd);
    const float4* xs4 = reinterpret_cast<const float4*>(xs);

    float acc[8][4];
    #pragma unroll
    for (int r = 0; r < 8; ++r)
        #pragma unroll
        for (int j = 0; j < 4; ++j) acc[r][j] = 0.f;

    #pragma unroll
    for (int s = 0; s < 8; ++s) {
        const int ko = s * 16 + kl;
        const float4 a = w0[ko], b_ = w1[ko], c = w2[ko], d = w3[ko];
        #pragma unroll
        for (int r = 0; r < 8; ++r) {
            const float4 xv = xs4[r * 128 + ko];
            fma4(acc[r][0], xv, a);
            fma4(acc[r][1], xv, b_);
            fma4(acc[r][2], xv, c);
            fma4(acc[r][3], xv, d);
        }
    }

    #pragma unroll
    for (int r = 0; r < 8; ++r)
        #pragma unroll
        for (int j = 0; j < 4; ++j)
            acc[r][j] = red16(acc[r][j]);

    if (kl == 0) {
        const float4 bv = *reinterpret_cast<const float4*>(bb + h0);
        const int hl = wave * 16 + g * 4;
        #pragma unroll
        for (int r = 0; r < 8; ++r) {
            float4 o;
            o.x = leaky(acc[r][0] + bv.x);
            o.y = leaky(acc[r][1] + bv.y);
            o.z = leaky(acc[r][2] + bv.z);
            o.w = leaky(acc[r][3] + bv.w);
            *reinterpret_cast<float4*>(&hbuf[r][hl]) = o;
        }
    }
    __syncthreads();

    // Phase B: partial projections over the 64-h slice.
    if (t < 128) {
        const int r = t >> 4, o = t & 15;
        const float4* wf1 = reinterpret_cast<const float4*>(Wf + (size_t)o * (3 * Hh) + hc * 64);
        const float4* wf2 = reinterpret_cast<const float4*>(Wf + (size_t)o * (3 * Hh) + Hh + hc * 64);
        const float4* wf3 = reinterpret_cast<const float4*>(Wf + (size_t)o * (3 * Hh) + 2 * Hh + hc * 64);
        const float4* hv  = reinterpret_cast<const float4*>(&hbuf[r][0]);

        float s1 = 0.f, s2 = 0.f, s3 = 0.f;
        #pragma unroll
        for (int k = 0; k < 16; ++k) {
            const float4 h4 = hv[k];
            fma4(s1, wf1[k], h4);
            fma4(s2, wf2[k], h4);
            if (m == 0) fma4(s3, wf3[k], h4);
        }

        const int bl = rs * 8 + r;
        const int b = bl >> 8, l = bl & 255;
        const size_t idx = ((size_t)(b * Oo + o)) * L + l;
        if (m == 0) {
            PA[(size_t)hc * SLAB + idx] = s1;
            PB[(size_t)hc * SLAB + idx] = 0.5f * s2;
            PD[(size_t)hc * SLAB + idx] = s3;
        } else {
            PA[(size_t)(4 + hc) * SLAB + idx] = 0.5f * s2;
            PB[(size_t)(4 + hc) * SLAB + idx] = -s1;
        }
    }
}

// ---------------------------------------------------------------------------
// K2: partial-reduce + cumsum + epilogue (byte-identical to R4).
// grid = 32 bo x 16 i-chunks = 512 blocks, 256 thr.
//   out[bo,i,j] = A[j] + Bv[i] + bf[o] + (C[j]-C[i-1])/(j-i+1+1e-9)
// i = j+1 numerator exactly 0 (identical LDS values) -> no 1e9 blowup.
// ---------------------------------------------------------------------------
__global__ __launch_bounds__(256) void out_kernel(
    const float* __restrict__ PA, const float* __restrict__ PB,
    const float* __restrict__ PD, const float* __restrict__ bf,
    float* __restrict__ out)
{
    const int bo = blockIdx.x >> 4;    // 0..31
    const int ig = blockIdx.x & 15;    // i-chunk of 16
    const int t  = threadIdx.x;

    __shared__ float Asm[L], Bsm[L], ca[L], cb[L];
    {
        float a = 0.f, bsum = 0.f, d = 0.f;
        #pragma unroll
        for (int s = 0; s < 8; ++s) {
            a    += PA[(size_t)s * SLAB + (size_t)bo * L + t];
            bsum += PB[(size_t)s * SLAB + (size_t)bo * L + t];
        }
        #pragma unroll
        for (int s = 0; s < 4; ++s)
            d += PD[(size_t)s * SLAB + (size_t)bo * L + t];
        Asm[t] = a; Bsm[t] = bsum; ca[t] = d;
    }
    __syncthreads();

    float* src = ca;
    float* dst = cb;
    #pragma unroll
    for (int off = 1; off < L; off <<= 1) {
        const float s = src[t] + ((t >= off) ? src[t - off] : 0.f);
        dst[t] = s;
        __syncthreads();
        float* tmp = src; src = dst; dst = tmp;
    }
    // src[l] = inclusive prefix C[l]

    const float bfv = bf[bo & (Oo - 1)];
    const int j0 = (t & 63) * 4;
    const int is = t >> 6;

    const float4 Av = *reinterpret_cast<const float4*>(Asm + j0);
    const float4 Cv = *reinterpret_cast<const float4*>(src + j0);

    #pragma unroll
    for (int ii = 0; ii < 4; ++ii) {
        const int i = ig * 16 + is * 4 + ii;
        const float cp   = (i > 0) ? src[i - 1] : 0.f;
        const float base = Bsm[i] + bfv;
        float4 r;
        r.x = Av.x + base + (Cv.x - cp) / ((float)(j0 + 0 - i + 1) + 1e-9f);
        r.y = Av.y + base + (Cv.y - cp) / ((float)(j0 + 1 - i + 1) + 1e-9f);
        r.z = Av.z + base + (Cv.z - cp) / ((float)(j0 + 2 - i + 1) + 1e-9f);
        r.w = Av.w + base + (Cv.w - cp) / ((float)(j0 + 3 - i + 1) + 1e-9f);
        *reinterpret_cast<float4*>(out + ((size_t)bo * L + i) * L + j0) = r;
    }
}

// ---------------------------------------------------------------------------
extern "C" void kernel_launch(void* const* d_in, const int* in_sizes, int n_in,
                              void* d_out, int out_size, void* d_ws, size_t ws_size,
                              hipStream_t stream)
{
    const float* x  = (const float*)d_in[0];
    const float* W1 = (const float*)d_in[1];
    const float* b1 = (const float*)d_in[2];
    const float* W2 = (const float*)d_in[3];
    const float* b2 = (const float*)d_in[4];
    const float* Wf = (const float*)d_in[5];
    const float* bf = (const float*)d_in[6];
    float* out = (float*)d_out;

    float* ws = (float*)d_ws;
    float* PA = ws;                       // 8 * SLAB
    float* PB = PA + 8 * (size_t)SLAB;    // 8 * SLAB
    float* PD = PB + 8 * (size_t)SLAB;    // 4 * SLAB

    hipLaunchKernelGGL(mlp_proj_kernel, dim3(BL / 8, 4, 2), dim3(256), 0, stream,
                       x, W1, b1, W2, b2, Wf, PA, PB, PD);
    hipLaunchKernelGGL(out_kernel, dim3(NBO * 16), dim3(256), 0, stream,
                       PA, PB, PD, bf, out);
}